// Round 6
// baseline (279.051 us; speedup 1.0000x reference)
//
#include <hip/hip_runtime.h>
#include <math.h>
#include <stdint.h>

// Problem constants
#define NB 4
#define NC 128
#define NP 4096
#define KNN 10

// ---------------- ws layout (float-slot offsets) ----------------
// Xcat (bf16 u16) : [B][N][512]   @ 0         (4194304 float-slots = 16MB)
// UV   (f32)      : [B][N][512]   @ 4194304
// Mbuf (f32)      : [B][N][256]   @ 12582912  (Y3 aliases, [B][N][128])
// idx  (i32)      : [B][N][10]    @ 16777216
// W1cat (bf16)    : [256][128]    @ 16941056
// W2cat (bf16)    : [512][128]    @ 16957440
// W3b  (bf16)     : [128][512]    @ 16990208
// stats (f32)     : [8192]        @ 17022976
// KNN scratch aliases UV region (all KNN kernels run before stage-1 GEMM).
// ALL plane-major [slot][16384] for coalescing:
//   candd: [80][16384]  @ UV+0
//   tq   : [16384]      @ UV+1310720
//   cd   : [192][16384] @ UV+1327104
//   ci   : [192][16384] @ UV+4472832 (int)
//   cnt  : [16384]      @ UV+7618560 (int)

__device__ __forceinline__ uint16_t f2bf(float f) {
  uint32_t u = __float_as_uint(f);
  u += 0x7fffu + ((u >> 16) & 1u);      // RNE
  return (uint16_t)(u >> 16);
}

__device__ __forceinline__ void async16(const void* g, void* l) {
  __builtin_amdgcn_global_load_lds(
      (const __attribute__((address_space(1))) unsigned int*)g,
      (__attribute__((address_space(3))) unsigned int*)l,
      16, 0, 0);
}

typedef __bf16 bf16x8 __attribute__((ext_vector_type(8)));
typedef float f32x4 __attribute__((ext_vector_type(4)));

__global__ void k_prep(const float* __restrict__ W1, const float* __restrict__ W2,
                       const float* __restrict__ W3,
                       uint16_t* __restrict__ W1cat, uint16_t* __restrict__ W2cat,
                       uint16_t* __restrict__ W3b,
                       float* __restrict__ stats, int* __restrict__ cnt) {
  int t = blockIdx.x * 256 + threadIdx.x;
  if (t < 32768) {
    int o = t >> 7, c = t & 127;
    float v;
    if (o < 128) v = W1[o * 256 + c] - W1[o * 256 + 128 + c];     // A1 = W1a - W1b
    else         v = W1[(o - 128) * 256 + 128 + c];               // B1 = W1b
    W1cat[t] = f2bf(v);
  } else if (t < 98304) {
    int t2 = t - 32768;
    int o = t2 >> 7, c = t2 & 127;
    float v;
    if (o < 256) v = W2[o * 256 + c] - W2[o * 256 + 128 + c];     // A2
    else         v = W2[(o - 256) * 256 + 128 + c];               // B2
    W2cat[t2] = f2bf(v);
  } else if (t < 163840) {
    int t2 = t - 98304;
    W3b[t2] = f2bf(W3[t2]);
  } else if (t < 163840 + 8192) {
    stats[t - 163840] = 0.f;
  } else if (t < 163840 + 8192 + 16384) {
    cnt[t - 163840 - 8192] = 0;
  }
}

// features [B][128][4096] (f32) -> Xcat[b][n][0:128] (bf16)
__global__ void k_trans_feat(const float* __restrict__ feat, uint16_t* __restrict__ Xcat) {
  __shared__ float tile[32][33];
  int bid = blockIdx.x;           // 2048
  int b = bid >> 9;
  int r = bid & 511;
  int n0 = (r >> 2) << 5;
  int c0 = (r & 3) << 5;
  int tx = threadIdx.x & 31, ty = threadIdx.x >> 5;   // 256 threads
#pragma unroll
  for (int i = 0; i < 4; i++) {
    int c = c0 + ty + i * 8;
    tile[ty + i * 8][tx] = feat[(b * 128 + c) * 4096 + n0 + tx];
  }
  __syncthreads();
#pragma unroll
  for (int i = 0; i < 4; i++) {
    int n = n0 + ty + i * 8;
    Xcat[((b * 4096 + n) * 512) + c0 + tx] = f2bf(tile[tx][ty + i * 8]);
  }
}

// ---------------- KNN: exact subsampled-threshold scheme ----------------
// d = (qsq + |p|^2) - 2 q.p  with explicit fmaf: bit-identical in thr & collect.
// Phase A: threshold candidates from SUBSET = first 1024 points (8 chunks of 128).
// Writes plane-major candd[(ch*10+i)][row] (coalesced).
__global__ void k_knn_thr(const float* __restrict__ coords, float* __restrict__ candd) {
  __shared__ float4 sp[128];
  int L = blockIdx.x;             // 512 = b(4) x qb(16) x ch(8)
  int ch = L & 7;
  int qb = (L >> 3) & 15;
  int b = L >> 7;
  int m0 = ch << 7;               // subset points ch*128 .. +127  (all < 1024)
  const float* cb = coords + b * 12288;
  int t = threadIdx.x;
  if (t < 128) {
    int m = m0 + t;
    float x = cb[m], y = cb[4096 + m], z = cb[8192 + m];
    sp[t] = make_float4(x, y, z, x * x + y * y + z * z);
  }
  __syncthreads();
  int q = (qb << 8) + t;
  float qx = cb[q], qy = cb[4096 + q], qz = cb[8192 + q];
  float qsq = fmaf(qx, qx, fmaf(qy, qy, qz * qz));
  float d10[10];
#pragma unroll
  for (int i = 0; i < 10; i++) d10[i] = 1e30f;
#pragma unroll 2
  for (int mm = 0; mm < 128; mm++) {
    float4 p = sp[mm];
    float dot = fmaf(qx, p.x, fmaf(qy, p.y, qz * p.z));
    float s = qsq + p.w;
    float d = fmaf(-2.f, dot, s);
    d = (m0 + mm == q) ? 1e30f : d;       // self-exclusion (subset may contain q)
    if (d < d10[9]) {
      float carry = d;
#pragma unroll
      for (int i = 0; i < 10; i++) {
        float lo = fminf(d10[i], carry);
        carry = fmaxf(d10[i], carry);
        d10[i] = lo;
      }
    }
  }
  int row = b * 4096 + q;
#pragma unroll
  for (int i = 0; i < 10; i++) candd[(ch * 10 + i) * 16384 + row] = d10[i];
}

// Phase B: per query merge 80 values (plane-major, coalesced) -> 10th smallest
__global__ void k_knn_merge(const float* __restrict__ candd, float* __restrict__ tq) {
  int q = blockIdx.x * 64 + threadIdx.x;  // 256 blocks x 64
  float d10[10];
#pragma unroll
  for (int i = 0; i < 10; i++) d10[i] = 1e30f;
  for (int j = 0; j < 80; j++) {
    float carry = candd[j * 16384 + q];
    if (carry < d10[9]) {
#pragma unroll
      for (int i = 0; i < 10; i++) {
        float lo = fminf(d10[i], carry);
        carry = fmaxf(d10[i], carry);
        d10[i] = lo;
      }
    }
  }
  tq[q] = d10[9];
}

// Phase C: full rescan (bit-identical distance), collect indices with d <= thr
// Writes plane-major cd/ci[pos][row].
__global__ void k_knn_collect(const float* __restrict__ coords, const float* __restrict__ tq,
                              int* __restrict__ cnt, float* __restrict__ cd, int* __restrict__ ci) {
  __shared__ float4 sp[128];
  int L = blockIdx.x;             // 2048 = b(4) x qb(16) x ch(32)
  int ch = L & 31;
  int qb = (L >> 5) & 15;
  int b = L >> 9;
  int m0 = ch << 7;
  const float* cb = coords + b * 12288;
  int t = threadIdx.x;
  if (t < 128) {
    int m = m0 + t;
    float x = cb[m], y = cb[4096 + m], z = cb[8192 + m];
    sp[t] = make_float4(x, y, z, x * x + y * y + z * z);
  }
  __syncthreads();
  int q = (qb << 8) + t;
  int row = b * 4096 + q;
  float qx = cb[q], qy = cb[4096 + q], qz = cb[8192 + q];
  float qsq = fmaf(qx, qx, fmaf(qy, qy, qz * qz));
  float thr = tq[row];
  for (int mm = 0; mm < 128; mm++) {
    float4 p = sp[mm];
    float dot = fmaf(qx, p.x, fmaf(qy, p.y, qz * p.z));
    float s = qsq + p.w;
    float d = fmaf(-2.f, dot, s);
    int m = m0 + mm;
    d = (m == q) ? 1e30f : d;             // self-exclusion folded into d
    if (d <= thr) {
      int pos = atomicAdd(&cnt[row], 1);
      if (pos < 192) { cd[pos * 16384 + row] = d; ci[pos * 16384 + row] = m; }
    }
  }
}

// Phase D: exact (d, idx) lexicographic top-10 (plane-major, coalesced reads)
__global__ void k_knn_final(const int* __restrict__ cnt, const float* __restrict__ cd,
                            const int* __restrict__ ci, int* __restrict__ idx) {
  int row = blockIdx.x * 64 + threadIdx.x;  // 256 blocks x 64
  int c = cnt[row]; c = c < 192 ? c : 192;
  float d10[10]; int i10[10];
#pragma unroll
  for (int i = 0; i < 10; i++) { d10[i] = 1e30f; i10[i] = 0x7fffffff; }
  for (int j = 0; j < c; j++) {
    float cdv = cd[j * 16384 + row]; int civ = ci[j * 16384 + row];
    if (cdv < d10[9] || (cdv == d10[9] && civ < i10[9])) {
#pragma unroll
      for (int i = 0; i < 10; i++) {
        bool lt = (cdv < d10[i]) || (cdv == d10[i] && civ < i10[i]);
        float nd = lt ? cdv : d10[i]; int ni = lt ? civ : i10[i];
        float pd = lt ? d10[i] : cdv; int pi2 = lt ? i10[i] : civ;
        d10[i] = nd; i10[i] = ni; cdv = pd; civ = pi2;
      }
    }
  }
#pragma unroll
  for (int i = 0; i < 10; i++) idx[row * 10 + i] = i10[i];
}

// ---------------- bf16 MFMA GEMM ----------------
// Y[p][o] = sum_k X[p][xoff+k] * W[o][k]   (X,W bf16; Y f32)
// BM=128, BN=64, BK=64. 256 threads = 4 waves (2x2). mfma 16x16x32.
__global__ __launch_bounds__(256) void k_gemm_bf(
    const uint16_t* __restrict__ Xb, int ldx, int xoff,
    const uint16_t* __restrict__ Wb, int ldw,
    float* __restrict__ Y, int ldy, int K) {
  __shared__ __align__(16) uint8_t lds[49152];
  const int t = threadIdx.x;
  const int l = t & 63;
  const int wid = t >> 6;
  const int wr = wid & 1, wc = wid >> 1;
  const int p0 = blockIdx.x * 128;
  const int o0 = blockIdx.y * 64;

  const int rA = l >> 3;                         // row within 8-row chunk
  const int cbp = ((l & 7) ^ rA) << 4;           // pre-swizzled byte col (staging)
  const int swl = (l & 7) << 4;                  // read-side swizzle XOR

  f32x4 acc[4][2];
#pragma unroll
  for (int mi = 0; mi < 4; mi++)
#pragma unroll
    for (int ni = 0; ni < 2; ni++) acc[mi][ni] = (f32x4)0.f;

  auto stage = [&](int k0, int buf) {
    const uint16_t* Xs_ = Xb + (size_t)p0 * ldx + xoff + k0;
    const uint16_t* Ws_ = Wb + (size_t)o0 * ldw + k0;
#pragma unroll
    for (int cc = 0; cc < 4; cc++) {
      int c = wid * 4 + cc;                      // A chunk 0..15 -> rows c*8..c*8+8
      const uint8_t* g = (const uint8_t*)(Xs_ + (size_t)(c * 8 + rA) * ldx) + cbp;
      async16(g, &lds[buf * 16384 + c * 1024]);
    }
#pragma unroll
    for (int cc = 0; cc < 2; cc++) {
      int c = wid * 2 + cc;                      // B chunk 0..7
      const uint8_t* g = (const uint8_t*)(Ws_ + (size_t)(c * 8 + rA) * ldw) + cbp;
      async16(g, &lds[32768 + buf * 8192 + c * 1024]);
    }
  };

  auto compute = [&](int buf) {
    const uint8_t* Ab = &lds[buf * 16384];
    const uint8_t* Bb = &lds[32768 + buf * 8192];
#pragma unroll
    for (int ks = 0; ks < 2; ks++) {
      int cb = ks * 64 + ((l >> 4) << 4);
      bf16x8 bfr[2];
#pragma unroll
      for (int ni = 0; ni < 2; ni++) {
        int n = wc * 32 + ni * 16 + (l & 15);
        bfr[ni] = *(const bf16x8*)(Bb + n * 128 + (cb ^ swl));
      }
#pragma unroll
      for (int mi = 0; mi < 4; mi++) {
        int m = wr * 64 + mi * 16 + (l & 15);
        bf16x8 afr = *(const bf16x8*)(Ab + m * 128 + (cb ^ swl));
        acc[mi][0] = __builtin_amdgcn_mfma_f32_16x16x32_bf16(afr, bfr[0], acc[mi][0], 0, 0, 0);
        acc[mi][1] = __builtin_amdgcn_mfma_f32_16x16x32_bf16(afr, bfr[1], acc[mi][1], 0, 0, 0);
      }
    }
  };

  const int nsteps = K >> 6;
  stage(0, 0);
  for (int s = 0; s < nsteps; s++) {
    __syncthreads();                              // drains in-flight loads
    if (s + 1 < nsteps) stage((s + 1) << 6, (s + 1) & 1);
    compute(s & 1);
  }

#pragma unroll
  for (int mi = 0; mi < 4; mi++)
#pragma unroll
    for (int ni = 0; ni < 2; ni++) {
      int col = o0 + wc * 32 + ni * 16 + (l & 15);
      int row0 = p0 + wr * 64 + mi * 16 + (l >> 4) * 4;
#pragma unroll
      for (int j = 0; j < 4; j++)
        Y[(size_t)(row0 + j) * ldy + col] = acc[mi][ni][j];
    }
}

// Gather pass (fp32 UV)
template <int O>
__global__ void k_gather(const float* __restrict__ UV, int ld, int voff,
                         const int* __restrict__ idx,
                         float* __restrict__ M,
                         float* __restrict__ T1, float* __restrict__ T2) {
  int L = blockIdx.x;             // 1024 blocks
  int rx = L & 7;
  int b = rx >> 1;
  int j = ((L >> 3) << 1) + (rx & 1);
  int n0 = j << 4;
  int o = threadIdx.x;
  float a1 = 0.f, a2 = 0.f;
  for (int pi = 0; pi < 16; pi++) {
    int row = b * 4096 + n0 + pi;
    float u = UV[row * ld + o];
    float s1 = 0.f, s2 = 0.f, vmax = -1e30f;
#pragma unroll
    for (int jj = 0; jj < KNN; jj++) {
      int m = idx[row * 10 + jj];
      float v = UV[(b * 4096 + m) * ld + voff + o];
      s1 += v;
      float x = u + v;
      s2 = fmaf(x, x, s2);
      vmax = fmaxf(vmax, v);
    }
    M[row * O + o] = vmax;
    a1 += 10.f * u + s1;
    a2 += s2;
  }
  atomicAdd(&T1[b * O + o], a1);
  atomicAdd(&T2[b * O + o], a2);
}

// x = lrelu((U + maxV - mu) * rsqrt(var+eps)) -> Xcat[:, coff:coff+O] (bf16)
template <int O>
__global__ void k_passB(const float* __restrict__ UV, int ld,
                        const float* __restrict__ M, int coff,
                        const float* __restrict__ T1, const float* __restrict__ T2,
                        uint16_t* __restrict__ Xcat) {
  int t = blockIdx.x * 256 + threadIdx.x;
  int o = t & (O - 1);
  int pn = t / O;
  int b = pn >> 12;
  float mu = T1[b * O + o] * (1.f / 40960.f);
  float e2 = T2[b * O + o] * (1.f / 40960.f);
  float inv = rsqrtf(e2 - mu * mu + 1e-5f);
  float x = (UV[pn * ld + o] + M[pn * O + o] - mu) * inv;
  Xcat[pn * 512 + coff + o] = f2bf(x >= 0.f ? x : 0.2f * x);
}

__global__ void k_stats3(const float* __restrict__ Y3, float* __restrict__ T1, float* __restrict__ T2) {
  int L = blockIdx.x;             // 1024
  int rx = L & 7;
  int b = rx >> 1;
  int j = ((L >> 3) << 1) + (rx & 1);
  int n0 = j << 4;
  int o = threadIdx.x;            // 128
  float a1 = 0.f, a2 = 0.f;
  for (int pi = 0; pi < 16; pi++) {
    float y = Y3[(b * 4096 + n0 + pi) * 128 + o];
    a1 += y;
    a2 = fmaf(y, y, a2);
  }
  atomicAdd(&T1[b * 128 + o], a1);
  atomicAdd(&T2[b * 128 + o], a2);
}

// out[b][o][n] = lrelu((Y3[b][n][o]-mu)*inv)  (transposing write)
__global__ void k_out(const float* __restrict__ Y3, const float* __restrict__ T1,
                      const float* __restrict__ T2, float* __restrict__ out) {
  __shared__ float tile[32][33];
  int bid = blockIdx.x;           // 2048
  int b = bid >> 9;
  int r = bid & 511;
  int n0 = (r >> 2) << 5;
  int o0 = (r & 3) << 5;
  int tx = threadIdx.x & 31, ty = threadIdx.x >> 5;
  int o = o0 + tx;
  float mu = T1[b * 128 + o] * (1.f / 4096.f);
  float e2 = T2[b * 128 + o] * (1.f / 4096.f);
  float inv = rsqrtf(e2 - mu * mu + 1e-5f);
#pragma unroll
  for (int i = 0; i < 4; i++) {
    int n = n0 + ty + i * 8;
    float v = (Y3[(b * 4096 + n) * 128 + o] - mu) * inv;
    tile[ty + i * 8][tx] = v >= 0.f ? v : 0.2f * v;
  }
  __syncthreads();
#pragma unroll
  for (int i = 0; i < 4; i++) {
    int oo = o0 + ty + i * 8;
    out[(b * 128 + oo) * 4096 + n0 + tx] = tile[tx][ty + i * 8];
  }
}

extern "C" void kernel_launch(void* const* d_in, const int* in_sizes, int n_in,
                              void* d_out, int out_size, void* d_ws, size_t ws_size,
                              hipStream_t stream) {
  const float* coords   = (const float*)d_in[0];
  const float* features = (const float*)d_in[1];
  const float* W1       = (const float*)d_in[2];
  const float* W2       = (const float*)d_in[3];
  const float* W3       = (const float*)d_in[4];
  float* out = (float*)d_out;

  float*    ws    = (float*)d_ws;
  uint16_t* Xcat  = (uint16_t*)ws;                 // bf16 [4][4096][512]
  float*    UV    = ws + 4194304;
  float*    Mbuf  = ws + 12582912;
  float*    Y3    = Mbuf;                          // alias (M dead by fuse GEMM)
  int*      idxb  = (int*)(ws + 16777216);
  uint16_t* W1cat = (uint16_t*)(ws + 16941056);
  uint16_t* W2cat = (uint16_t*)(ws + 16957440);
  uint16_t* W3b   = (uint16_t*)(ws + 16990208);
  float*    stats = ws + 17022976;
  // KNN scratch aliases UV region (all KNN kernels complete before stage-1 GEMM)
  float* candd = UV;
  float* tq    = UV + 1310720;
  float* cd    = UV + 1327104;
  int*   ci    = (int*)(UV + 4472832);
  int*   cnt   = (int*)(UV + 7618560);

  k_prep<<<736, 256, 0, stream>>>(W1, W2, W3, W1cat, W2cat, W3b, stats, cnt);
  k_trans_feat<<<2048, 256, 0, stream>>>(features, Xcat);
  k_knn_thr<<<512, 256, 0, stream>>>(coords, candd);
  k_knn_merge<<<256, 64, 0, stream>>>(candd, tq);
  k_knn_collect<<<2048, 256, 0, stream>>>(coords, tq, cnt, cd, ci);
  k_knn_final<<<256, 64, 0, stream>>>(cnt, cd, ci, idxb);

  // stage 1: UV = Xcat[:, 0:128] @ W1cat^T  (O=256)
  k_gemm_bf<<<dim3(128, 4), 256, 0, stream>>>(Xcat, 512, 0, W1cat, 128, UV, 256, 128);
  k_gather<128><<<1024, 128, 0, stream>>>(UV, 256, 128, idxb, Mbuf, stats + 0, stats + 512);
  k_passB<128><<<8192, 256, 0, stream>>>(UV, 256, Mbuf, 128, stats + 0, stats + 512, Xcat);

  // stage 2: UV = Xcat[:, 128:256] @ W2cat^T (O=512)
  k_gemm_bf<<<dim3(128, 8), 256, 0, stream>>>(Xcat, 512, 128, W2cat, 128, UV, 512, 128);
  k_gather<256><<<1024, 256, 0, stream>>>(UV, 512, 256, idxb, Mbuf, stats + 1024, stats + 2048);
  k_passB<256><<<16384, 256, 0, stream>>>(UV, 512, Mbuf, 256, stats + 1024, stats + 2048, Xcat);

  // fuse: Y3 = Xcat[:, 0:512] @ W3b^T (O=128)
  k_gemm_bf<<<dim3(128, 2), 256, 0, stream>>>(Xcat, 512, 0, W3b, 512, Y3, 128, 512);
  k_stats3<<<1024, 128, 0, stream>>>(Y3, stats + 3072, stats + 3584);
  k_out<<<2048, 256, 0, stream>>>(Y3, stats + 3072, stats + 3584, out);
}

// Round 7
// 215.603 us; speedup vs baseline: 1.2943x; 1.2943x over previous
//
#include <hip/hip_runtime.h>
#include <math.h>
#include <stdint.h>

// Problem constants
#define NB 4
#define NC 128
#define NP 4096
#define KNN 10

// ---------------- ws layout (float-slot offsets) ----------------
// Xcat (bf16 u16) : [B][N][512]   @ 0         (4194304 float-slots = 16MB)
// UV   (f32)      : [B][N][512]   @ 4194304
// Mbuf (f32)      : [B][N][256]   @ 12582912  (Y3 aliases, [B][N][128])
// idx  (i32)      : [B][N][10]    @ 16777216
// W1cat (bf16)    : [256][128]    @ 16941056
// W2cat (bf16)    : [512][128]    @ 16957440
// W3b  (bf16)     : [128][512]    @ 16990208
// stats (f32)     : [8192]        @ 17022976
// KNN scratch aliases UV region (all KNN kernels run before stage-1 GEMM).
// ROW-major (wave-per-query consumes a contiguous candidate list):
//   candd: [16384][80]  @ UV+0
//   tq   : [16384]      @ UV+1310720
//   cd   : [16384][192] @ UV+1327104
//   ci   : [16384][192] @ UV+4472832 (int)
//   cnt  : [16384]      @ UV+7618560 (int)

__device__ __forceinline__ uint16_t f2bf(float f) {
  uint32_t u = __float_as_uint(f);
  u += 0x7fffu + ((u >> 16) & 1u);      // RNE
  return (uint16_t)(u >> 16);
}

__device__ __forceinline__ void async16(const void* g, void* l) {
  __builtin_amdgcn_global_load_lds(
      (const __attribute__((address_space(1))) unsigned int*)g,
      (__attribute__((address_space(3))) unsigned int*)l,
      16, 0, 0);
}

// float -> order-preserving uint32 (all finite values)
__device__ __forceinline__ uint32_t fsort(float f) {
  uint32_t u = __float_as_uint(f);
  return (u & 0x80000000u) ? ~u : (u | 0x80000000u);
}
__device__ __forceinline__ float funsort(uint32_t k) {
  uint32_t u = (k & 0x80000000u) ? (k & 0x7fffffffu) : ~k;
  return __uint_as_float(u);
}

typedef __bf16 bf16x8 __attribute__((ext_vector_type(8)));
typedef float f32x4 __attribute__((ext_vector_type(4)));

__global__ void k_prep(const float* __restrict__ W1, const float* __restrict__ W2,
                       const float* __restrict__ W3,
                       uint16_t* __restrict__ W1cat, uint16_t* __restrict__ W2cat,
                       uint16_t* __restrict__ W3b,
                       float* __restrict__ stats, int* __restrict__ cnt) {
  int t = blockIdx.x * 256 + threadIdx.x;
  if (t < 32768) {
    int o = t >> 7, c = t & 127;
    float v;
    if (o < 128) v = W1[o * 256 + c] - W1[o * 256 + 128 + c];     // A1 = W1a - W1b
    else         v = W1[(o - 128) * 256 + 128 + c];               // B1 = W1b
    W1cat[t] = f2bf(v);
  } else if (t < 98304) {
    int t2 = t - 32768;
    int o = t2 >> 7, c = t2 & 127;
    float v;
    if (o < 256) v = W2[o * 256 + c] - W2[o * 256 + 128 + c];     // A2
    else         v = W2[(o - 256) * 256 + 128 + c];               // B2
    W2cat[t2] = f2bf(v);
  } else if (t < 163840) {
    int t2 = t - 98304;
    W3b[t2] = f2bf(W3[t2]);
  } else if (t < 163840 + 8192) {
    stats[t - 163840] = 0.f;
  } else if (t < 163840 + 8192 + 16384) {
    cnt[t - 163840 - 8192] = 0;
  }
}

// features [B][128][4096] (f32) -> Xcat[b][n][0:128] (bf16)
__global__ void k_trans_feat(const float* __restrict__ feat, uint16_t* __restrict__ Xcat) {
  __shared__ float tile[32][33];
  int bid = blockIdx.x;           // 2048
  int b = bid >> 9;
  int r = bid & 511;
  int n0 = (r >> 2) << 5;
  int c0 = (r & 3) << 5;
  int tx = threadIdx.x & 31, ty = threadIdx.x >> 5;   // 256 threads
#pragma unroll
  for (int i = 0; i < 4; i++) {
    int c = c0 + ty + i * 8;
    tile[ty + i * 8][tx] = feat[(b * 128 + c) * 4096 + n0 + tx];
  }
  __syncthreads();
#pragma unroll
  for (int i = 0; i < 4; i++) {
    int n = n0 + ty + i * 8;
    Xcat[((b * 4096 + n) * 512) + c0 + tx] = f2bf(tile[tx][ty + i * 8]);
  }
}

// ---------------- KNN: exact subsampled-threshold scheme ----------------
// d = (qsq + |p|^2) - 2 q.p  with explicit fmaf: bit-identical in thr & collect.
// Phase A: per-chunk sorted top-10 over SUBSET = first 1024 points.
__global__ void k_knn_thr(const float* __restrict__ coords, float* __restrict__ candd) {
  __shared__ float4 sp[128];
  int L = blockIdx.x;             // 512 = b(4) x qb(16) x ch(8)
  int ch = L & 7;
  int qb = (L >> 3) & 15;
  int b = L >> 7;
  int m0 = ch << 7;               // subset points ch*128 .. +127  (all < 1024)
  const float* cb = coords + b * 12288;
  int t = threadIdx.x;
  if (t < 128) {
    int m = m0 + t;
    float x = cb[m], y = cb[4096 + m], z = cb[8192 + m];
    sp[t] = make_float4(x, y, z, x * x + y * y + z * z);
  }
  __syncthreads();
  int q = (qb << 8) + t;
  float qx = cb[q], qy = cb[4096 + q], qz = cb[8192 + q];
  float qsq = fmaf(qx, qx, fmaf(qy, qy, qz * qz));
  float d10[10];
#pragma unroll
  for (int i = 0; i < 10; i++) d10[i] = 1e30f;
#pragma unroll 2
  for (int mm = 0; mm < 128; mm++) {
    float4 p = sp[mm];
    float dot = fmaf(qx, p.x, fmaf(qy, p.y, qz * p.z));
    float s = qsq + p.w;
    float d = fmaf(-2.f, dot, s);
    d = (m0 + mm == q) ? 1e30f : d;       // self-exclusion (subset may contain q)
    if (d < d10[9]) {
      float carry = d;
#pragma unroll
      for (int i = 0; i < 10; i++) {
        float lo = fminf(d10[i], carry);
        carry = fmaxf(d10[i], carry);
        d10[i] = lo;
      }
    }
  }
  int row = b * 4096 + q;
#pragma unroll
  for (int i = 0; i < 10; i++) candd[row * 80 + ch * 10 + i] = d10[i];
}

// Phase B: wave-per-query exact 10th-smallest of the 80 subset candidates.
// 64 lanes load the row (coalesced); 10x {u32 min-butterfly, mask}.
// Duplicate values collapse only LOOSENS the threshold (still a superset).
__global__ void k_knn_merge(const float* __restrict__ candd, float* __restrict__ tq) {
  int gw = blockIdx.x * 4 + (threadIdx.x >> 6);   // 4096 blocks -> 16384 waves
  int l = threadIdx.x & 63;
  const float* cp = candd + (size_t)gw * 80;
  uint32_t k0 = fsort(cp[l]);
  uint32_t k1 = (l < 16) ? fsort(cp[64 + l]) : 0xFFFFFFFFu;
  uint32_t g = 0;
#pragma unroll
  for (int it = 0; it < 10; it++) {
    uint32_t m = k0 < k1 ? k0 : k1;
#pragma unroll
    for (int s = 1; s < 64; s <<= 1) {
      uint32_t o = __shfl_xor(m, s);
      m = o < m ? o : m;
    }
    g = m;
    if (it < 9) {
      if (k0 == m) k0 = 0xFFFFFFFFu;
      else if (k1 == m) k1 = 0xFFFFFFFFu;
    }
  }
  if (l == 0) tq[gw] = funsort(g);
}

// Phase C: full rescan (bit-identical distance), collect indices with d <= thr.
// Row-major scatter writes.
__global__ void k_knn_collect(const float* __restrict__ coords, const float* __restrict__ tq,
                              int* __restrict__ cnt, float* __restrict__ cd, int* __restrict__ ci) {
  __shared__ float4 sp[128];
  int L = blockIdx.x;             // 2048 = b(4) x qb(16) x ch(32)
  int ch = L & 31;
  int qb = (L >> 5) & 15;
  int b = L >> 9;
  int m0 = ch << 7;
  const float* cb = coords + b * 12288;
  int t = threadIdx.x;
  if (t < 128) {
    int m = m0 + t;
    float x = cb[m], y = cb[4096 + m], z = cb[8192 + m];
    sp[t] = make_float4(x, y, z, x * x + y * y + z * z);
  }
  __syncthreads();
  int q = (qb << 8) + t;
  int row = b * 4096 + q;
  float qx = cb[q], qy = cb[4096 + q], qz = cb[8192 + q];
  float qsq = fmaf(qx, qx, fmaf(qy, qy, qz * qz));
  float thr = tq[row];
  for (int mm = 0; mm < 128; mm++) {
    float4 p = sp[mm];
    float dot = fmaf(qx, p.x, fmaf(qy, p.y, qz * p.z));
    float s = qsq + p.w;
    float d = fmaf(-2.f, dot, s);
    int m = m0 + mm;
    d = (m == q) ? 1e30f : d;             // self-exclusion folded into d
    if (d <= thr) {
      int pos = atomicAdd(&cnt[row], 1);
      if (pos < 192) { cd[row * 192 + pos] = d; ci[row * 192 + pos] = m; }
    }
  }
}

// Phase D: wave-per-query exact (d, idx) lexicographic top-10 of <=192 candidates.
// u64 key = (sortable(d) << 32) | idx  -> single u64 min == lexicographic min.
__global__ void k_knn_final(const int* __restrict__ cnt, const float* __restrict__ cd,
                            const int* __restrict__ ci, int* __restrict__ idxout) {
  int gw = blockIdx.x * 4 + (threadIdx.x >> 6);   // 4096 blocks -> 16384 waves
  int l = threadIdx.x & 63;
  int c = cnt[gw]; c = c < 192 ? c : 192;
  unsigned long long k0, k1, k2;
  {
    const float* cdr = cd + (size_t)gw * 192;
    const int* cir = ci + (size_t)gw * 192;
    int j0 = l, j1 = 64 + l, j2 = 128 + l;
    k0 = (j0 < c) ? (((unsigned long long)fsort(cdr[j0]) << 32) | (uint32_t)cir[j0]) : ~0ULL;
    k1 = (j1 < c) ? (((unsigned long long)fsort(cdr[j1]) << 32) | (uint32_t)cir[j1]) : ~0ULL;
    k2 = (j2 < c) ? (((unsigned long long)fsort(cdr[j2]) << 32) | (uint32_t)cir[j2]) : ~0ULL;
  }
  uint32_t keep[10];
#pragma unroll
  for (int it = 0; it < 10; it++) {
    unsigned long long m = k0 < k1 ? k0 : k1;
    m = k2 < m ? k2 : m;
#pragma unroll
    for (int s = 1; s < 64; s <<= 1) {
      unsigned long long o = __shfl_xor(m, s);
      m = o < m ? o : m;
    }
    keep[it] = (uint32_t)(m & 0xffffffffu);
    if (k0 == m) k0 = ~0ULL;
    else if (k1 == m) k1 = ~0ULL;
    else if (k2 == m) k2 = ~0ULL;
  }
  if (l == 0) {
#pragma unroll
    for (int i = 0; i < 10; i++) idxout[gw * 10 + i] = (int)keep[i];
  }
}

// ---------------- bf16 MFMA GEMM ----------------
// Y[p][o] = sum_k X[p][xoff+k] * W[o][k]   (X,W bf16; Y f32)
// BM=128, BN=64, BK=64. 256 threads = 4 waves (2x2). mfma 16x16x32.
__global__ __launch_bounds__(256) void k_gemm_bf(
    const uint16_t* __restrict__ Xb, int ldx, int xoff,
    const uint16_t* __restrict__ Wb, int ldw,
    float* __restrict__ Y, int ldy, int K) {
  __shared__ __align__(16) uint8_t lds[49152];
  const int t = threadIdx.x;
  const int l = t & 63;
  const int wid = t >> 6;
  const int wr = wid & 1, wc = wid >> 1;
  const int p0 = blockIdx.x * 128;
  const int o0 = blockIdx.y * 64;

  const int rA = l >> 3;                         // row within 8-row chunk
  const int cbp = ((l & 7) ^ rA) << 4;           // pre-swizzled byte col (staging)
  const int swl = (l & 7) << 4;                  // read-side swizzle XOR

  f32x4 acc[4][2];
#pragma unroll
  for (int mi = 0; mi < 4; mi++)
#pragma unroll
    for (int ni = 0; ni < 2; ni++) acc[mi][ni] = (f32x4)0.f;

  auto stage = [&](int k0, int buf) {
    const uint16_t* Xs_ = Xb + (size_t)p0 * ldx + xoff + k0;
    const uint16_t* Ws_ = Wb + (size_t)o0 * ldw + k0;
#pragma unroll
    for (int cc = 0; cc < 4; cc++) {
      int c = wid * 4 + cc;                      // A chunk 0..15 -> rows c*8..c*8+8
      const uint8_t* g = (const uint8_t*)(Xs_ + (size_t)(c * 8 + rA) * ldx) + cbp;
      async16(g, &lds[buf * 16384 + c * 1024]);
    }
#pragma unroll
    for (int cc = 0; cc < 2; cc++) {
      int c = wid * 2 + cc;                      // B chunk 0..7
      const uint8_t* g = (const uint8_t*)(Ws_ + (size_t)(c * 8 + rA) * ldw) + cbp;
      async16(g, &lds[32768 + buf * 8192 + c * 1024]);
    }
  };

  auto compute = [&](int buf) {
    const uint8_t* Ab = &lds[buf * 16384];
    const uint8_t* Bb = &lds[32768 + buf * 8192];
#pragma unroll
    for (int ks = 0; ks < 2; ks++) {
      int cb = ks * 64 + ((l >> 4) << 4);
      bf16x8 bfr[2];
#pragma unroll
      for (int ni = 0; ni < 2; ni++) {
        int n = wc * 32 + ni * 16 + (l & 15);
        bfr[ni] = *(const bf16x8*)(Bb + n * 128 + (cb ^ swl));
      }
#pragma unroll
      for (int mi = 0; mi < 4; mi++) {
        int m = wr * 64 + mi * 16 + (l & 15);
        bf16x8 afr = *(const bf16x8*)(Ab + m * 128 + (cb ^ swl));
        acc[mi][0] = __builtin_amdgcn_mfma_f32_16x16x32_bf16(afr, bfr[0], acc[mi][0], 0, 0, 0);
        acc[mi][1] = __builtin_amdgcn_mfma_f32_16x16x32_bf16(afr, bfr[1], acc[mi][1], 0, 0, 0);
      }
    }
  };

  const int nsteps = K >> 6;
  stage(0, 0);
  for (int s = 0; s < nsteps; s++) {
    __syncthreads();                              // drains in-flight loads
    if (s + 1 < nsteps) stage((s + 1) << 6, (s + 1) & 1);
    compute(s & 1);
  }

#pragma unroll
  for (int mi = 0; mi < 4; mi++)
#pragma unroll
    for (int ni = 0; ni < 2; ni++) {
      int col = o0 + wc * 32 + ni * 16 + (l & 15);
      int row0 = p0 + wr * 64 + mi * 16 + (l >> 4) * 4;
#pragma unroll
      for (int j = 0; j < 4; j++)
        Y[(size_t)(row0 + j) * ldy + col] = acc[mi][ni][j];
    }
}

// Gather pass (fp32 UV)
template <int O>
__global__ void k_gather(const float* __restrict__ UV, int ld, int voff,
                         const int* __restrict__ idx,
                         float* __restrict__ M,
                         float* __restrict__ T1, float* __restrict__ T2) {
  int L = blockIdx.x;             // 1024 blocks
  int rx = L & 7;
  int b = rx >> 1;
  int j = ((L >> 3) << 1) + (rx & 1);
  int n0 = j << 4;
  int o = threadIdx.x;
  float a1 = 0.f, a2 = 0.f;
  for (int pi = 0; pi < 16; pi++) {
    int row = b * 4096 + n0 + pi;
    float u = UV[row * ld + o];
    float s1 = 0.f, s2 = 0.f, vmax = -1e30f;
#pragma unroll
    for (int jj = 0; jj < KNN; jj++) {
      int m = idx[row * 10 + jj];
      float v = UV[(b * 4096 + m) * ld + voff + o];
      s1 += v;
      float x = u + v;
      s2 = fmaf(x, x, s2);
      vmax = fmaxf(vmax, v);
    }
    M[row * O + o] = vmax;
    a1 += 10.f * u + s1;
    a2 += s2;
  }
  atomicAdd(&T1[b * O + o], a1);
  atomicAdd(&T2[b * O + o], a2);
}

// x = lrelu((U + maxV - mu) * rsqrt(var+eps)) -> Xcat[:, coff:coff+O] (bf16)
template <int O>
__global__ void k_passB(const float* __restrict__ UV, int ld,
                        const float* __restrict__ M, int coff,
                        const float* __restrict__ T1, const float* __restrict__ T2,
                        uint16_t* __restrict__ Xcat) {
  int t = blockIdx.x * 256 + threadIdx.x;
  int o = t & (O - 1);
  int pn = t / O;
  int b = pn >> 12;
  float mu = T1[b * O + o] * (1.f / 40960.f);
  float e2 = T2[b * O + o] * (1.f / 40960.f);
  float inv = rsqrtf(e2 - mu * mu + 1e-5f);
  float x = (UV[pn * ld + o] + M[pn * O + o] - mu) * inv;
  Xcat[pn * 512 + coff + o] = f2bf(x >= 0.f ? x : 0.2f * x);
}

__global__ void k_stats3(const float* __restrict__ Y3, float* __restrict__ T1, float* __restrict__ T2) {
  int L = blockIdx.x;             // 1024
  int rx = L & 7;
  int b = rx >> 1;
  int j = ((L >> 3) << 1) + (rx & 1);
  int n0 = j << 4;
  int o = threadIdx.x;            // 128
  float a1 = 0.f, a2 = 0.f;
  for (int pi = 0; pi < 16; pi++) {
    float y = Y3[(b * 4096 + n0 + pi) * 128 + o];
    a1 += y;
    a2 = fmaf(y, y, a2);
  }
  atomicAdd(&T1[b * 128 + o], a1);
  atomicAdd(&T2[b * 128 + o], a2);
}

// out[b][o][n] = lrelu((Y3[b][n][o]-mu)*inv)  (transposing write)
__global__ void k_out(const float* __restrict__ Y3, const float* __restrict__ T1,
                      const float* __restrict__ T2, float* __restrict__ out) {
  __shared__ float tile[32][33];
  int bid = blockIdx.x;           // 2048
  int b = bid >> 9;
  int r = bid & 511;
  int n0 = (r >> 2) << 5;
  int o0 = (r & 3) << 5;
  int tx = threadIdx.x & 31, ty = threadIdx.x >> 5;
  int o = o0 + tx;
  float mu = T1[b * 128 + o] * (1.f / 4096.f);
  float e2 = T2[b * 128 + o] * (1.f / 4096.f);
  float inv = rsqrtf(e2 - mu * mu + 1e-5f);
#pragma unroll
  for (int i = 0; i < 4; i++) {
    int n = n0 + ty + i * 8;
    float v = (Y3[(b * 4096 + n) * 128 + o] - mu) * inv;
    tile[ty + i * 8][tx] = v >= 0.f ? v : 0.2f * v;
  }
  __syncthreads();
#pragma unroll
  for (int i = 0; i < 4; i++) {
    int oo = o0 + ty + i * 8;
    out[(b * 128 + oo) * 4096 + n0 + tx] = tile[tx][ty + i * 8];
  }
}

extern "C" void kernel_launch(void* const* d_in, const int* in_sizes, int n_in,
                              void* d_out, int out_size, void* d_ws, size_t ws_size,
                              hipStream_t stream) {
  const float* coords   = (const float*)d_in[0];
  const float* features = (const float*)d_in[1];
  const float* W1       = (const float*)d_in[2];
  const float* W2       = (const float*)d_in[3];
  const float* W3       = (const float*)d_in[4];
  float* out = (float*)d_out;

  float*    ws    = (float*)d_ws;
  uint16_t* Xcat  = (uint16_t*)ws;                 // bf16 [4][4096][512]
  float*    UV    = ws + 4194304;
  float*    Mbuf  = ws + 12582912;
  float*    Y3    = Mbuf;                          // alias (M dead by fuse GEMM)
  int*      idxb  = (int*)(ws + 16777216);
  uint16_t* W1cat = (uint16_t*)(ws + 16941056);
  uint16_t* W2cat = (uint16_t*)(ws + 16957440);
  uint16_t* W3b   = (uint16_t*)(ws + 16990208);
  float*    stats = ws + 17022976;
  // KNN scratch aliases UV region (all KNN kernels complete before stage-1 GEMM)
  float* candd = UV;
  float* tq    = UV + 1310720;
  float* cd    = UV + 1327104;
  int*   ci    = (int*)(UV + 4472832);
  int*   cnt   = (int*)(UV + 7618560);

  k_prep<<<736, 256, 0, stream>>>(W1, W2, W3, W1cat, W2cat, W3b, stats, cnt);
  k_trans_feat<<<2048, 256, 0, stream>>>(features, Xcat);
  k_knn_thr<<<512, 256, 0, stream>>>(coords, candd);
  k_knn_merge<<<4096, 256, 0, stream>>>(candd, tq);
  k_knn_collect<<<2048, 256, 0, stream>>>(coords, tq, cnt, cd, ci);
  k_knn_final<<<4096, 256, 0, stream>>>(cnt, cd, ci, idxb);

  // stage 1: UV = Xcat[:, 0:128] @ W1cat^T  (O=256)
  k_gemm_bf<<<dim3(128, 4), 256, 0, stream>>>(Xcat, 512, 0, W1cat, 128, UV, 256, 128);
  k_gather<128><<<1024, 128, 0, stream>>>(UV, 256, 128, idxb, Mbuf, stats + 0, stats + 512);
  k_passB<128><<<8192, 256, 0, stream>>>(UV, 256, Mbuf, 128, stats + 0, stats + 512, Xcat);

  // stage 2: UV = Xcat[:, 128:256] @ W2cat^T (O=512)
  k_gemm_bf<<<dim3(128, 8), 256, 0, stream>>>(Xcat, 512, 128, W2cat, 128, UV, 512, 128);
  k_gather<256><<<1024, 256, 0, stream>>>(UV, 512, 256, idxb, Mbuf, stats + 1024, stats + 2048);
  k_passB<256><<<16384, 256, 0, stream>>>(UV, 512, Mbuf, 256, stats + 1024, stats + 2048, Xcat);

  // fuse: Y3 = Xcat[:, 0:512] @ W3b^T (O=128)
  k_gemm_bf<<<dim3(128, 2), 256, 0, stream>>>(Xcat, 512, 0, W3b, 512, Y3, 128, 512);
  k_stats3<<<1024, 128, 0, stream>>>(Y3, stats + 3072, stats + 3584);
  k_out<<<2048, 256, 0, stream>>>(Y3, stats + 3072, stats + 3584, out);
}